// Round 5
// baseline (615.329 us; speedup 1.0000x reference)
//
#include <hip/hip_runtime.h>
#include <math.h>

#define NQ 8
#define NSTATE 256
#define NLAYERS 4

// |c| below this fraction of the term-magnitude sum S marks the element for
// fp64 rescue (kernel B). Non-rescued lanes: added log-error <= ~5e-3, 12x
// below the passing absmax 0.0625. Per-lane trigger prob ~0.26%.
#define RESCUE_TAU 1e-3f
// NaN sentinel written by kernel A, detected by kernel B.
#define NAN_BITS 0x7fc00000u

// ---------------------------------------------------------------------------
// Kernel 1: 8-qubit statevector sim (amplitude head only — harness keeps only
// Re(log psi), so the phase circuit is dead). 1 block, 256 threads.
// Writes ws[0] = amplitude scalar (float).
// ---------------------------------------------------------------------------
__global__ __launch_bounds__(256) void qsim_kernel(
    const float* __restrict__ pa, const float* __restrict__ ca,
    float* __restrict__ ws)
{
  __shared__ float bR[2][NSTATE];
  __shared__ float bI[2][NSTATE];
  __shared__ float U[NQ][8];
  __shared__ float part[4][NQ];

  const int t = threadIdx.x;

  bR[0][t] = 0.0625f;   // H^8 |0>
  bI[0][t] = 0.0f;
  int cur = 0;
  __syncthreads();

  for (int l = 0; l < NLAYERS; ++l) {
    if (t < NQ) {
      const float thz = pa[l*24 + t*3 + 0];
      const float thx = pa[l*24 + t*3 + 1];
      const float thy = pa[l*24 + t*3 + 2];
      const float cz_ = cosf(0.5f*thz), sz_ = sinf(0.5f*thz);
      const float cx_ = cosf(0.5f*thx), sx_ = sinf(0.5f*thx);
      const float cy_ = cosf(0.5f*thy), sy_ = sinf(0.5f*thy);
      const float m00r =  cx_*cz_, m00i = -cx_*sz_;
      const float m01r =  sx_*sz_, m01i = -sx_*cz_;
      const float m10r = -sx_*sz_, m10i = -sx_*cz_;
      const float m11r =  cx_*cz_, m11i =  cx_*sz_;
      U[t][0] = cy_*m00r - sy_*m10r;  U[t][1] = cy_*m00i - sy_*m10i;
      U[t][2] = cy_*m01r - sy_*m11r;  U[t][3] = cy_*m01i - sy_*m11i;
      U[t][4] = sy_*m00r + cy_*m10r;  U[t][5] = sy_*m00i + cy_*m10i;
      U[t][6] = sy_*m01r + cy_*m11r;  U[t][7] = sy_*m01i + cy_*m11i;
    }
    __syncthreads();

    for (int i = 0; i < NQ; ++i) {
      const int mask = 1 << (7 - i);
      const int b    = (t & mask) ? 1 : 0;
      const int prt  = t ^ mask;
      const float sr = bR[cur][t],   si = bI[cur][t];
      const float pr = bR[cur][prt], pi = bI[cur][prt];
      const float urr = U[i][b*6],           uri = U[i][b*6 + 1];
      const float upr = U[i][b*4 + (1-b)*2], upi = U[i][b*4 + (1-b)*2 + 1];
      bR[cur^1][t] = urr*sr - uri*si + upr*pr - upi*pi;
      bI[cur^1][t] = urr*si + uri*sr + upr*pi + upi*pr;
      __syncthreads();
      cur ^= 1;
    }

    // entangling monomial: reverse walk (forward order: i asc, j asc)
    int idx = t, sgn = 0;
    for (int i = NQ - 2; i >= 0; --i) {
      for (int j = NQ - 1; j > i; --j) {
        const int mi = 1 << (7 - i), mj = 1 << (7 - j);
        if (((i + j) & 1) == 0) { if (idx & mi) idx ^= mj; }            // CNOT
        else                    { if ((idx & mi) && (idx & mj)) sgn ^= 1; } // CZ
      }
    }
    float gr = bR[cur][idx], gi = bI[cur][idx];
    if (sgn) { gr = -gr; gi = -gi; }
    bR[cur^1][t] = gr;
    bI[cur^1][t] = gi;
    __syncthreads();
    cur ^= 1;
  }

  const float fr = bR[cur][t], fi = bI[cur][t];
  const float prob = fr*fr + fi*fi;
  const int wave = t >> 6, lane = t & 63;
#pragma unroll
  for (int i = 0; i < NQ; ++i) {
    float v = (t & (1 << (7 - i))) ? -prob : prob;
#pragma unroll
    for (int off = 32; off > 0; off >>= 1) v += __shfl_down(v, off, 64);
    if (lane == 0) part[wave][i] = v;
  }
  __syncthreads();
  if (t == 0) {
    float acc = 0.0f;
#pragma unroll
    for (int i = 0; i < NQ; ++i)
      acc = fmaf(ca[i], part[0][i] + part[1][i] + part[2][i] + part[3][i], acc);
    ws[0] = acc;   // amplitude scalar
  }
}

// ---------------------------------------------------------------------------
// Kernel A (hot): per-element MLP 8->32->32->1, PURE fp32 — no fp64 anywhere
// (round-4 lesson: an inline fp64 branch inflated VALU cycles 6x via codegen
// damage; the rescue now lives in a separate tiny kernel).
// Structure = round-2's proven loop (j-tile 8, k-inner, 1 elem/thread).
// Cancelled elements (|c| < tau*S) get a NaN sentinel for kernel B.
// ---------------------------------------------------------------------------
__global__ __launch_bounds__(256) void mlp_kernel(
    const float* __restrict__ x,
    const float* __restrict__ W1, const float* __restrict__ b1,
    const float* __restrict__ W2, const float* __restrict__ b2,
    const float* __restrict__ W3, const float* __restrict__ b3,
    const float* __restrict__ ws, float* __restrict__ out, int B)
{
  const int e = blockIdx.x * 256 + threadIdx.x;
  if (e >= B) return;

  const float4* __restrict__ x4 = (const float4*)x;
  const float4 xa = x4[2*e];
  const float4 xb = x4[2*e + 1];
  const float xv[8] = {xa.x, xa.y, xa.z, xa.w, xb.x, xb.y, xb.z, xb.w};

  // layer 1
  float h1[32];
#pragma unroll
  for (int j = 0; j < 32; ++j) {
    float a = b1[j];
#pragma unroll
    for (int k = 0; k < 8; ++k)
      a = fmaf(xv[k], W1[k*32 + j], a);
    h1[j] = fmaxf(a, 0.0f);
  }

  // layers 2+3, j-tiled (8 wide), k-inner; S = sum of |terms| of final dot
  float c = b3[0];
  float S = fabsf(b3[0]);
#pragma unroll
  for (int jt = 0; jt < 4; ++jt) {
    float a2[8];
#pragma unroll
    for (int u = 0; u < 8; ++u)
      a2[u] = b2[jt*8 + u];
#pragma unroll
    for (int k = 0; k < 32; ++k) {
      const float h = h1[k];
#pragma unroll
      for (int u = 0; u < 8; ++u)
        a2[u] = fmaf(h, W2[k*32 + jt*8 + u], a2[u]);
    }
#pragma unroll
    for (int u = 0; u < 8; ++u) {
      const float r  = fmaxf(a2[u], 0.0f);
      const float w3 = W3[jt*8 + u];
      c = fmaf(r, w3, c);
      S = fmaf(r, fabsf(w3), S);
    }
  }

  float res = ws[0] + logf(fabsf(c));
  if (fabsf(c) < RESCUE_TAU * S) res = __uint_as_float(NAN_BITS);
  out[e] = res;
}

// ---------------------------------------------------------------------------
// Kernel B (rescue): 64 blocks scan out[] for NaN sentinels, compact the
// indices into an LDS queue, then re-solve ONLY those elements in fp64 with
// math bit-identical to the previously-passing all-fp64 kernel. Expected
// ~2600 rescued elements over B=1M -> ~40 per block; fp64 work is packed
// into full waves instead of smeared 1-lane-per-wave.
// ---------------------------------------------------------------------------
#define SCAN_PER_BLOCK 16384   // 64 elems/thread, 16 float4 passes
#define QCAP 1024

__global__ __launch_bounds__(256) void rescue_kernel(
    const float* __restrict__ x,
    const float* __restrict__ W1, const float* __restrict__ b1,
    const float* __restrict__ W2, const float* __restrict__ b2,
    const float* __restrict__ W3, const float* __restrict__ b3,
    const float* __restrict__ ws, float* __restrict__ out, int B)
{
  __shared__ int lcount;
  __shared__ int lidx[QCAP];
  const int t = threadIdx.x;
  if (t == 0) lcount = 0;
  __syncthreads();

  const int base = blockIdx.x * SCAN_PER_BLOCK;
  const float4* __restrict__ o4 = (const float4*)out;
#pragma unroll
  for (int p = 0; p < 16; ++p) {
    const int e4 = (base >> 2) + p * 256 + t;       // float4 index
    if (e4 * 4 < B) {
      const float4 v = o4[e4];
      const float vv[4] = {v.x, v.y, v.z, v.w};
#pragma unroll
      for (int q = 0; q < 4; ++q) {
        if (vv[q] != vv[q]) {                       // NaN sentinel
          const int pos = atomicAdd(&lcount, 1);
          if (pos < QCAP) lidx[pos] = e4 * 4 + q;
        }
      }
    }
  }
  __syncthreads();

  const int n = lcount < QCAP ? lcount : QCAP;
  const float amp = ws[0];
  for (int j = t; j < n; j += 256) {
    const int e = lidx[j];
    const float4* __restrict__ x4 = (const float4*)x;
    const float4 xa = x4[2*e];
    const float4 xb = x4[2*e + 1];
    const double xd[8] = {(double)xa.x, (double)xa.y, (double)xa.z, (double)xa.w,
                          (double)xb.x, (double)xb.y, (double)xb.z, (double)xb.w};

    float h1r[32];
#pragma unroll
    for (int jj = 0; jj < 32; ++jj) {
      double a = (double)b1[jj];
#pragma unroll
      for (int k = 0; k < 8; ++k)
        a = fma(xd[k], (double)W1[k*32 + jj], a);
      h1r[jj] = a > 0.0 ? (float)a : 0.0f;
    }

    double cd = (double)b3[0];
#pragma unroll
    for (int jt = 0; jt < 4; ++jt) {
      double a2d[8];
#pragma unroll
      for (int u = 0; u < 8; ++u)
        a2d[u] = (double)b2[jt*8 + u];
#pragma unroll
      for (int k = 0; k < 32; ++k) {
        const double h = (double)h1r[k];
#pragma unroll
        for (int u = 0; u < 8; ++u)
          a2d[u] = fma(h, (double)W2[k*32 + jt*8 + u], a2d[u]);
      }
#pragma unroll
      for (int u = 0; u < 8; ++u)
        cd = fma(a2d[u] > 0.0 ? a2d[u] : 0.0, (double)W3[jt*8 + u], cd);
    }
    out[e] = amp + logf(fabsf((float)cd));
  }
}

extern "C" void kernel_launch(void* const* d_in, const int* in_sizes, int n_in,
                              void* d_out, int out_size, void* d_ws, size_t ws_size,
                              hipStream_t stream) {
  (void)n_in; (void)out_size; (void)ws_size;
  const float* x  = (const float*)d_in[0];
  const float* qa = (const float*)d_in[1];
  const float* ca = (const float*)d_in[3];
  const float* W1 = (const float*)d_in[5];
  const float* b1 = (const float*)d_in[6];
  const float* W2 = (const float*)d_in[7];
  const float* b2 = (const float*)d_in[8];
  const float* W3 = (const float*)d_in[9];
  const float* b3 = (const float*)d_in[10];
  float* ws = (float*)d_ws;
  const int B = in_sizes[0] / NQ;

  hipLaunchKernelGGL(qsim_kernel, dim3(1), dim3(256), 0, stream, qa, ca, ws);
  hipLaunchKernelGGL(mlp_kernel, dim3((B + 255) / 256), dim3(256), 0, stream,
                     x, W1, b1, W2, b2, W3, b3, ws, (float*)d_out, B);
  hipLaunchKernelGGL(rescue_kernel,
                     dim3((B + SCAN_PER_BLOCK - 1) / SCAN_PER_BLOCK), dim3(256),
                     0, stream,
                     x, W1, b1, W2, b2, W3, b3, ws, (float*)d_out, B);
}

// Round 6
// 263.006 us; speedup vs baseline: 2.3396x; 2.3396x over previous
//
#include <hip/hip_runtime.h>
#include <math.h>

#define NQ 8
#define NSTATE 256
#define NLAYERS 4

// |c| below this fraction of the term-magnitude sum S marks the element for
// fp64 rescue (kernel B). Non-rescued lanes: added log-error <= ~5e-3, 12x
// below the passing absmax 0.0625. Per-lane trigger prob ~0.3%.
#define RESCUE_TAU 1e-3f
// NaN sentinel written by kernel A, detected by kernel B via exact bit match.
#define NAN_BITS 0x7fc00000u

// ---------------------------------------------------------------------------
// Kernel 1: 8-qubit statevector sim (amplitude head only — harness keeps only
// Re(log psi), so the phase circuit is dead). 1 block, 256 threads.
// Writes ws[0] = amplitude scalar (float).
// ---------------------------------------------------------------------------
__global__ __launch_bounds__(256) void qsim_kernel(
    const float* __restrict__ pa, const float* __restrict__ ca,
    float* __restrict__ ws)
{
  __shared__ float bR[2][NSTATE];
  __shared__ float bI[2][NSTATE];
  __shared__ float U[NQ][8];
  __shared__ float part[4][NQ];

  const int t = threadIdx.x;

  bR[0][t] = 0.0625f;   // H^8 |0>
  bI[0][t] = 0.0f;
  int cur = 0;
  __syncthreads();

  for (int l = 0; l < NLAYERS; ++l) {
    if (t < NQ) {
      const float thz = pa[l*24 + t*3 + 0];
      const float thx = pa[l*24 + t*3 + 1];
      const float thy = pa[l*24 + t*3 + 2];
      const float cz_ = cosf(0.5f*thz), sz_ = sinf(0.5f*thz);
      const float cx_ = cosf(0.5f*thx), sx_ = sinf(0.5f*thx);
      const float cy_ = cosf(0.5f*thy), sy_ = sinf(0.5f*thy);
      const float m00r =  cx_*cz_, m00i = -cx_*sz_;
      const float m01r =  sx_*sz_, m01i = -sx_*cz_;
      const float m10r = -sx_*sz_, m10i = -sx_*cz_;
      const float m11r =  cx_*cz_, m11i =  cx_*sz_;
      U[t][0] = cy_*m00r - sy_*m10r;  U[t][1] = cy_*m00i - sy_*m10i;
      U[t][2] = cy_*m01r - sy_*m11r;  U[t][3] = cy_*m01i - sy_*m11i;
      U[t][4] = sy_*m00r + cy_*m10r;  U[t][5] = sy_*m00i + cy_*m10i;
      U[t][6] = sy_*m01r + cy_*m11r;  U[t][7] = sy_*m01i + cy_*m11i;
    }
    __syncthreads();

    for (int i = 0; i < NQ; ++i) {
      const int mask = 1 << (7 - i);
      const int b    = (t & mask) ? 1 : 0;
      const int prt  = t ^ mask;
      const float sr = bR[cur][t],   si = bI[cur][t];
      const float pr = bR[cur][prt], pi = bI[cur][prt];
      const float urr = U[i][b*6],           uri = U[i][b*6 + 1];
      const float upr = U[i][b*4 + (1-b)*2], upi = U[i][b*4 + (1-b)*2 + 1];
      bR[cur^1][t] = urr*sr - uri*si + upr*pr - upi*pi;
      bI[cur^1][t] = urr*si + uri*sr + upr*pi + upi*pr;
      __syncthreads();
      cur ^= 1;
    }

    // entangling monomial: reverse walk (forward order: i asc, j asc)
    int idx = t, sgn = 0;
    for (int i = NQ - 2; i >= 0; --i) {
      for (int j = NQ - 1; j > i; --j) {
        const int mi = 1 << (7 - i), mj = 1 << (7 - j);
        if (((i + j) & 1) == 0) { if (idx & mi) idx ^= mj; }            // CNOT
        else                    { if ((idx & mi) && (idx & mj)) sgn ^= 1; } // CZ
      }
    }
    float gr = bR[cur][idx], gi = bI[cur][idx];
    if (sgn) { gr = -gr; gi = -gi; }
    bR[cur^1][t] = gr;
    bI[cur^1][t] = gi;
    __syncthreads();
    cur ^= 1;
  }

  const float fr = bR[cur][t], fi = bI[cur][t];
  const float prob = fr*fr + fi*fi;
  const int wave = t >> 6, lane = t & 63;
#pragma unroll
  for (int i = 0; i < NQ; ++i) {
    float v = (t & (1 << (7 - i))) ? -prob : prob;
#pragma unroll
    for (int off = 32; off > 0; off >>= 1) v += __shfl_down(v, off, 64);
    if (lane == 0) part[wave][i] = v;
  }
  __syncthreads();
  if (t == 0) {
    float acc = 0.0f;
#pragma unroll
    for (int i = 0; i < NQ; ++i)
      acc = fmaf(ca[i], part[0][i] + part[1][i] + part[2][i] + part[3][i], acc);
    ws[0] = acc;   // amplitude scalar
  }
}

// ---------------------------------------------------------------------------
// Kernel A (hot): per-element MLP 8->32->32->1, PURE fp32 — no fp64 anywhere
// (round-4 lesson: inline fp64 branch poisons codegen of the hot kernel).
// Cancelled elements (|c| < tau*S) get an exact NaN-bit sentinel for kernel B.
// This kernel measured ~30us in round 5 (fell out of top-5 at 477us rescue).
// ---------------------------------------------------------------------------
__global__ __launch_bounds__(256) void mlp_kernel(
    const float* __restrict__ x,
    const float* __restrict__ W1, const float* __restrict__ b1,
    const float* __restrict__ W2, const float* __restrict__ b2,
    const float* __restrict__ W3, const float* __restrict__ b3,
    const float* __restrict__ ws, float* __restrict__ out, int B)
{
  const int e = blockIdx.x * 256 + threadIdx.x;
  if (e >= B) return;

  const float4* __restrict__ x4 = (const float4*)x;
  const float4 xa = x4[2*e];
  const float4 xb = x4[2*e + 1];
  const float xv[8] = {xa.x, xa.y, xa.z, xa.w, xb.x, xb.y, xb.z, xb.w};

  // layer 1
  float h1[32];
#pragma unroll
  for (int j = 0; j < 32; ++j) {
    float a = b1[j];
#pragma unroll
    for (int k = 0; k < 8; ++k)
      a = fmaf(xv[k], W1[k*32 + j], a);
    h1[j] = fmaxf(a, 0.0f);
  }

  // layers 2+3, j-tiled (8 wide), k-inner; S = sum of |terms| of final dot
  float c = b3[0];
  float S = fabsf(b3[0]);
#pragma unroll
  for (int jt = 0; jt < 4; ++jt) {
    float a2[8];
#pragma unroll
    for (int u = 0; u < 8; ++u)
      a2[u] = b2[jt*8 + u];
#pragma unroll
    for (int k = 0; k < 32; ++k) {
      const float h = h1[k];
#pragma unroll
      for (int u = 0; u < 8; ++u)
        a2[u] = fmaf(h, W2[k*32 + jt*8 + u], a2[u]);
    }
#pragma unroll
    for (int u = 0; u < 8; ++u) {
      const float r  = fmaxf(a2[u], 0.0f);
      const float w3 = W3[jt*8 + u];
      c = fmaf(r, w3, c);
      S = fmaf(r, fabsf(w3), S);
    }
  }

  float res = ws[0] + logf(fabsf(c));
  if (fabsf(c) < RESCUE_TAU * S) res = __uint_as_float(NAN_BITS);
  out[e] = res;
}

// ---------------------------------------------------------------------------
// Kernel B (rescue), round-5 post-mortem rebuild: the LDS-queue version hit
// 256 VGPR with spill code smeared into the scan (WRITE_SIZE 29.6MB of
// scratch, 64 blocks, 0.7% occupancy, 477us). New structure: ONE THREAD PER
// ELEMENT, no queue, no atomics. Fast path = load 4B + bit-compare + exit
// (4MB coalesced, full GPU, ~2us). Only the ~3K sentinel threads (~1 per 4
// waves) run the fp64 body, whose math is bit-identical to the round-2
// all-fp64 kernel.
// ---------------------------------------------------------------------------
__global__ __launch_bounds__(256) void rescue_kernel(
    const float* __restrict__ x,
    const float* __restrict__ W1, const float* __restrict__ b1,
    const float* __restrict__ W2, const float* __restrict__ b2,
    const float* __restrict__ W3, const float* __restrict__ b3,
    const float* __restrict__ ws, float* __restrict__ out, int B)
{
  const int e = blockIdx.x * 256 + threadIdx.x;
  if (e >= B) return;
  if (__float_as_uint(out[e]) != NAN_BITS) return;   // cold branch below

  const float4* __restrict__ x4 = (const float4*)x;
  const float4 xa = x4[2*e];
  const float4 xb = x4[2*e + 1];
  const double xd[8] = {(double)xa.x, (double)xa.y, (double)xa.z, (double)xa.w,
                        (double)xb.x, (double)xb.y, (double)xb.z, (double)xb.w};

  float h1r[32];
#pragma unroll
  for (int j = 0; j < 32; ++j) {
    double a = (double)b1[j];
#pragma unroll
    for (int k = 0; k < 8; ++k)
      a = fma(xd[k], (double)W1[k*32 + j], a);
    h1r[j] = a > 0.0 ? (float)a : 0.0f;
  }

  double cd = (double)b3[0];
#pragma unroll
  for (int jt = 0; jt < 4; ++jt) {
    double a2d[8];
#pragma unroll
    for (int u = 0; u < 8; ++u)
      a2d[u] = (double)b2[jt*8 + u];
#pragma unroll
    for (int k = 0; k < 32; ++k) {
      const double h = (double)h1r[k];
#pragma unroll
      for (int u = 0; u < 8; ++u)
        a2d[u] = fma(h, (double)W2[k*32 + jt*8 + u], a2d[u]);
    }
#pragma unroll
    for (int u = 0; u < 8; ++u)
      cd = fma(a2d[u] > 0.0 ? a2d[u] : 0.0, (double)W3[jt*8 + u], cd);
  }

  out[e] = ws[0] + logf(fabsf((float)cd));
}

extern "C" void kernel_launch(void* const* d_in, const int* in_sizes, int n_in,
                              void* d_out, int out_size, void* d_ws, size_t ws_size,
                              hipStream_t stream) {
  (void)n_in; (void)out_size; (void)ws_size;
  const float* x  = (const float*)d_in[0];
  const float* qa = (const float*)d_in[1];
  const float* ca = (const float*)d_in[3];
  const float* W1 = (const float*)d_in[5];
  const float* b1 = (const float*)d_in[6];
  const float* W2 = (const float*)d_in[7];
  const float* b2 = (const float*)d_in[8];
  const float* W3 = (const float*)d_in[9];
  const float* b3 = (const float*)d_in[10];
  float* ws = (float*)d_ws;
  const int B = in_sizes[0] / NQ;
  const dim3 grid((B + 255) / 256);

  hipLaunchKernelGGL(qsim_kernel, dim3(1), dim3(256), 0, stream, qa, ca, ws);
  hipLaunchKernelGGL(mlp_kernel, grid, dim3(256), 0, stream,
                     x, W1, b1, W2, b2, W3, b3, ws, (float*)d_out, B);
  hipLaunchKernelGGL(rescue_kernel, grid, dim3(256), 0, stream,
                     x, W1, b1, W2, b2, W3, b3, ws, (float*)d_out, B);
}